// Round 17
// baseline (204.590 us; speedup 1.0000x reference)
//
#include <hip/hip_runtime.h>
#include <hip/hip_bf16.h>

#define DD 128

typedef short bf16x8 __attribute__((ext_vector_type(8)));
typedef float f32x4 __attribute__((ext_vector_type(4)));

__device__ __forceinline__ float bf2f_lo(unsigned int u) {
    union { unsigned int v; float f; } x; x.v = u << 16; return x.f;
}
__device__ __forceinline__ float bf2f_hi(unsigned int u) {
    union { unsigned int v; float f; } x; x.v = u & 0xFFFF0000u; return x.f;
}
__device__ __forceinline__ unsigned short f2bf(float f) {
    union { float f; unsigned int u; } x; x.f = f;
    unsigned int u = x.u;
    unsigned int r = (u + 0x7FFFu + ((u >> 16) & 1u)) >> 16;  // RNE
    return (unsigned short)r;
}

// bucket geometry: 128 dsts per bucket, 256 partition blocks (all CUs)
#define SBSH 7
#define SBN  128
#define NBP  256
#define NSBMAX 800
#define PKCAP 4096

// ---- merged: [0,NBP) sbhist | [NBP,NBP+80) weight convert ----
__global__ __launch_bounds__(256) void sbwc_k(
    const int* __restrict__ ei, int* __restrict__ bh,
    const float* __restrict__ Wenc, const float* __restrict__ W1,
    const float* __restrict__ W2, unsigned short* __restrict__ wb,
    int E, int chunk, int nsb)
{
    __shared__ int h4[4][NSBMAX];
    const int b = blockIdx.x;
    if (b < NBP) {                               // ---- sbhist ----
        int wid = threadIdx.x >> 6;
        for (int i = threadIdx.x; i < 4 * NSBMAX; i += 256) ((int*)h4)[i] = 0;
        __syncthreads();
        int beg = b * chunk, end = min(E, beg + chunk);
        for (int e = beg + threadIdx.x; e < end; e += 256)
            atomicAdd(&h4[wid][ei[E + e] >> SBSH], 1);
        __syncthreads();
        for (int i = threadIdx.x; i < nsb; i += 256)
            bh[i * NBP + b] = h4[0][i] + h4[1][i] + h4[2][i] + h4[3][i];
        return;
    }
    // ---- wcvt: Wenc(16384) | W1(32768) | W2(32768) -> bf16 ----
    int i = ((b - NBP) * 256 + threadIdx.x) * 4;
    if (i >= 81920) return;
    const float* src;
    int off;
    if (i < 16384)      { src = Wenc; off = 0; }
    else if (i < 49152) { src = W1;   off = 16384; }
    else                { src = W2;   off = 49152; }
    float4 v = *(const float4*)&src[i - off];
    ushort4 w;
    w.x = f2bf(v.x); w.y = f2bf(v.y); w.z = f2bf(v.z); w.w = f2bf(v.w);
    *(ushort4*)&wb[i] = w;
}

// ---- parallel scan stage 1: per-block (2048 elems) totals ----
__global__ __launch_bounds__(256) void pscan1_k(const int* __restrict__ bh,
                                                int* __restrict__ bsum, int ntot) {
    __shared__ int ws[4];
    int base = blockIdx.x * 2048 + threadIdx.x * 8;
    int s = 0;
    #pragma unroll
    for (int i = 0; i < 8; ++i) { int idx = base + i; if (idx < ntot) s += bh[idx]; }
    int lane = threadIdx.x & 63, wid = threadIdx.x >> 6;
    int ss = s;
    #pragma unroll
    for (int o = 1; o < 64; o <<= 1) { int t = __shfl_up(ss, o, 64); if (lane >= o) ss += t; }
    if (lane == 63) ws[wid] = ss;
    __syncthreads();
    if (threadIdx.x == 0) bsum[blockIdx.x] = ws[0] + ws[1] + ws[2] + ws[3];
}

// ---- scan stage 2 (fused): each block derives its own bsum prefix ----
__global__ __launch_bounds__(256) void pscan3_k(const int* __restrict__ bh,
                                                const int* __restrict__ bsum,
                                                int* __restrict__ bho, int ntot) {
    __shared__ int ws[4];
    __shared__ int boff;
    const int b = blockIdx.x;
    const int t = threadIdx.x;
    const int lane = t & 63, wid = t >> 6;

    int pv = (t < b) ? bsum[t] : 0;
    #pragma unroll
    for (int o = 32; o; o >>= 1) pv += __shfl_xor(pv, o, 64);
    if (lane == 0) ws[wid] = pv;
    __syncthreads();
    if (t == 0) boff = ws[0] + ws[1] + ws[2] + ws[3];
    __syncthreads();

    int base = b * 2048 + t * 8;
    int v[8]; int s = 0;
    #pragma unroll
    for (int i = 0; i < 8; ++i) { int idx = base + i; v[i] = (idx < ntot) ? bh[idx] : 0; s += v[i]; }
    int ss = s;
    #pragma unroll
    for (int o = 1; o < 64; o <<= 1) { int u = __shfl_up(ss, o, 64); if (lane >= o) ss += u; }
    if (lane == 63) ws[wid] = ss;
    __syncthreads();
    if (t == 0) { int c = 0; for (int w = 0; w < 4; ++w) { int u = ws[w]; ws[w] = c; c += u; } }
    __syncthreads();
    int excl = ss - s + ws[wid] + boff;
    #pragma unroll
    for (int i = 0; i < 8; ++i) {
        int idx = base + i;
        if (idx < ntot) bho[idx] = excl;
        excl += v[i];
    }
}

// ---- merged: [0,NBP) partition | [NBP,NBP+gm) gemm1 ----
__global__ __launch_bounds__(256) void pg_k(
    const int* __restrict__ ei, const int* __restrict__ ea,
    const int* __restrict__ bho, int* __restrict__ rec,
    const float* __restrict__ x, const unsigned short* __restrict__ Wb,
    unsigned short* __restrict__ Hb, const float* __restrict__ prelu_a,
    int E, int chunk, int nsb, int M)
{
    __shared__ int cur[NSBMAX];
    const int tid = threadIdx.x;

    if (blockIdx.x < NBP) {                      // ---- part ----
        int b = blockIdx.x;
        for (int i = tid; i < nsb; i += 256) cur[i] = bho[i * NBP + b];
        __syncthreads();
        int beg = b * chunk, end = min(E, beg + chunk);
        for (int e = beg + tid; e < end; e += 256) {
            int src = ei[e];
            int dst = ei[E + e];
            int2 aa = *(const int2*)&ea[2 * e];
            int pos = atomicAdd(&cur[dst >> SBSH], 1);
            rec[pos] = src | ((aa.x * 3 + aa.y) << 17) | ((dst & (SBN - 1)) << 21);
        }
        return;
    }

    // ---- gemm1 ----
    const int K = 128;
    const int wid = tid >> 6, lane = tid & 63;
    const float pa = prelu_a[0];
    const int r0 = (blockIdx.x - NBP) * 128 + wid * 32;
    const int rl = lane & 15, kb = (lane >> 4) * 8;

    bf16x8 af[2][4];
    #pragma unroll
    for (int rf = 0; rf < 2; ++rf) {
        int row = r0 + rf * 16 + rl; if (row > M - 1) row = M - 1;
        #pragma unroll
        for (int kf = 0; kf < 4; ++kf) {
            float4 v0 = *(const float4*)&x[(size_t)row * K + kf * 32 + kb];
            float4 v1 = *(const float4*)&x[(size_t)row * K + kf * 32 + kb + 4];
            v0.x = v0.x >= 0.f ? v0.x : pa * v0.x;
            v0.y = v0.y >= 0.f ? v0.y : pa * v0.y;
            v0.z = v0.z >= 0.f ? v0.z : pa * v0.z;
            v0.w = v0.w >= 0.f ? v0.w : pa * v0.w;
            v1.x = v1.x >= 0.f ? v1.x : pa * v1.x;
            v1.y = v1.y >= 0.f ? v1.y : pa * v1.y;
            v1.z = v1.z >= 0.f ? v1.z : pa * v1.z;
            v1.w = v1.w >= 0.f ? v1.w : pa * v1.w;
            bf16x8 t;
            t[0] = (short)f2bf(v0.x); t[1] = (short)f2bf(v0.y);
            t[2] = (short)f2bf(v0.z); t[3] = (short)f2bf(v0.w);
            t[4] = (short)f2bf(v1.x); t[5] = (short)f2bf(v1.y);
            t[6] = (short)f2bf(v1.z); t[7] = (short)f2bf(v1.w);
            af[rf][kf] = t;
        }
    }

    f32x4 acc[8][2];
    const f32x4 zz = {0.f, 0.f, 0.f, 0.f};
    #pragma unroll
    for (int nt = 0; nt < 8; ++nt) { acc[nt][0] = zz; acc[nt][1] = zz; }

    #pragma unroll
    for (int nt = 0; nt < 8; ++nt) {
        bf16x8 bf[4];
        #pragma unroll
        for (int kf = 0; kf < 4; ++kf)
            bf[kf] = *(const bf16x8*)&Wb[(size_t)(nt * 16 + rl) * K + kf * 32 + kb];
        #pragma unroll
        for (int rf = 0; rf < 2; ++rf)
            #pragma unroll
            for (int kf = 0; kf < 4; ++kf)
                acc[nt][rf] = __builtin_amdgcn_mfma_f32_16x16x32_bf16(af[rf][kf], bf[kf], acc[nt][rf], 0, 0, 0);
    }

    const int rq = (lane >> 4) * 4;
    #pragma unroll
    for (int nt = 0; nt < 8; ++nt) {
        int c = nt * 16 + rl;
        #pragma unroll
        for (int rf = 0; rf < 2; ++rf) {
            int rb = r0 + rf * 16 + rq;
            #pragma unroll
            for (int t = 0; t < 4; ++t) {
                int r = rb + t;
                if (r < M) Hb[(size_t)r * 128 + c] = f2bf(acc[nt][rf][t]);
            }
        }
    }
}

// ---- fused per-bucket sort + gather-reduce + 2-layer MLP ----
// LDS: emb12(5K) + hist/lstart(1K) + W1l(69.6K, aliased W2l) + U(67.6K)
//   U = pkl(16K)+aggl(34.8K) during agg; hidl(67.6K) after
__global__ __launch_bounds__(1024) void cam_k(
    const unsigned short* __restrict__ h,
    const int* __restrict__ rec,
    const int* __restrict__ bho,
    const float* __restrict__ emb1, const float* __restrict__ emb2,
    int* __restrict__ packed,
    const unsigned short* __restrict__ w1b, const float* __restrict__ b1,
    const unsigned short* __restrict__ w2b, const float* __restrict__ b2,
    float* __restrict__ out,
    int nsb, int M, int E)
{
    __shared__ float emb12[10][DD];
    __shared__ int hist[SBN];
    __shared__ int lstart[SBN];
    __shared__ int wsum[2];
    __shared__ unsigned short W1l[256][136];          // 69632 B; W2l aliases
    __shared__ char U[67584];                         // pkl+aggl | hidl
    int* pkl = (int*)U;                               // 16384 B
    unsigned short (*aggl)[136] = (unsigned short (*)[136])(U + 16384);  // 34816 B
    unsigned short (*hidl)[264] = (unsigned short (*)[264])U;            // 67584 B
    unsigned short (*W2l)[264] = (unsigned short (*)[264])&W1l[0][0];

    const int s = blockIdx.x;
    const int t = threadIdx.x;
    const int lane = t & 63, wid = t >> 6;
    const int rl = lane & 15, kb = (lane >> 4) * 8;
    const int rq = (lane >> 4) * 4;

    // stage W1 (bf16 copy) + emb table
    for (int idx = t; idx < 256 * 16; idx += 1024) {
        int n = idx >> 4, kq = idx & 15;
        *(ushort4*)&W1l[n][kq * 8] = *(const ushort4*)&w1b[(size_t)n * 128 + kq * 8];
        *(ushort4*)&W1l[n][kq * 8 + 4] = *(const ushort4*)&w1b[(size_t)n * 128 + kq * 8 + 4];
    }
    for (int i = t; i < 10 * DD; i += 1024) {
        int c = i >> 7, col = i & 127;
        float v;
        if (c == 9) v = emb1[4 * DD + col] + emb2[col];
        else        v = emb1[(c / 3) * DD + col] + emb2[(c % 3) * DD + col];
        emb12[c][col] = v;
    }
    int sb0 = bho[s * NBP];
    int sb1 = (s == nsb - 1) ? E : bho[(s + 1) * NBP];
    if (t < SBN) hist[t] = 0;
    __syncthreads();

    const bool inlds = (sb1 - sb0) <= PKCAP;

    for (int i = sb0 + t; i < sb1; i += 1024)
        atomicAdd(&hist[(rec[i] >> 21) & (SBN - 1)], 1);
    __syncthreads();

    int v = (t < SBN) ? hist[t] : 0;
    int ss = v;
    #pragma unroll
    for (int o = 1; o < 64; o <<= 1) { int u = __shfl_up(ss, o, 64); if (lane >= o) ss += u; }
    if (t < SBN && lane == 63) wsum[wid] = ss;
    __syncthreads();
    if (t == 0) { int c = 0; for (int w = 0; w < 2; ++w) { int x2 = wsum[w]; wsum[w] = c; c += x2; } }
    __syncthreads();
    if (t < SBN) {
        lstart[t] = ss - v + wsum[wid];
        hist[t] = 0;
    }
    __syncthreads();

    if (inlds) {
        for (int i = sb0 + t; i < sb1; i += 1024) {
            int r = rec[i];
            int dl = (r >> 21) & (SBN - 1);
            int pos = lstart[dl] + atomicAdd(&hist[dl], 1);
            pkl[pos] = r & 0x1FFFFF;
        }
    } else {
        for (int i = sb0 + t; i < sb1; i += 1024) {
            int r = rec[i];
            int dl = (r >> 21) & (SBN - 1);
            int pos = sb0 + lstart[dl] + atomicAdd(&hist[dl], 1);
            packed[pos] = r & 0x1FFFFF;
        }
    }
    __syncthreads();

    // aggregate: 16 waves x 8 rows -> aggl (bf16)
    const int n0 = s << SBSH;
    const int c2 = lane * 2;
    #pragma unroll
    for (int k = 0; k < SBN / 16; ++k) {
        int r = wid + k * 16;
        int n = n0 + r;
        if (n >= M) continue;
        int lbeg = lstart[r];
        int lend = lbeg + hist[r];
        unsigned int hn = *(const unsigned int*)&h[(size_t)n * DD + c2];
        float2 acc = {bf2f_lo(hn) + emb12[9][c2], bf2f_hi(hn) + emb12[9][c2 + 1]};
        if (inlds) {
            int e = lbeg;
            for (; e + 8 <= lend; e += 8) {
                int p[8]; unsigned int hv[8]; float2 m[8];
                #pragma unroll
                for (int i = 0; i < 8; ++i) p[i] = pkl[e + i];
                #pragma unroll
                for (int i = 0; i < 8; ++i)
                    hv[i] = *(const unsigned int*)&h[(size_t)(p[i] & 0x1FFFF) * DD + c2];
                #pragma unroll
                for (int i = 0; i < 8; ++i)
                    m[i] = *(const float2*)&emb12[(p[i] >> 17) & 15][c2];
                #pragma unroll
                for (int i = 0; i < 8; ++i) {
                    acc.x += bf2f_lo(hv[i]) + m[i].x;
                    acc.y += bf2f_hi(hv[i]) + m[i].y;
                }
            }
            for (; e < lend; ++e) {
                int p = pkl[e];
                unsigned int hv = *(const unsigned int*)&h[(size_t)(p & 0x1FFFF) * DD + c2];
                float2 m = *(const float2*)&emb12[(p >> 17) & 15][c2];
                acc.x += bf2f_lo(hv) + m.x;
                acc.y += bf2f_hi(hv) + m.y;
            }
        } else {
            int e = sb0 + lbeg, end = sb0 + lend;
            for (; e + 8 <= end; e += 8) {
                int p[8]; unsigned int hv[8]; float2 m[8];
                #pragma unroll
                for (int i = 0; i < 8; ++i) p[i] = packed[e + i];
                #pragma unroll
                for (int i = 0; i < 8; ++i)
                    hv[i] = *(const unsigned int*)&h[(size_t)(p[i] & 0x1FFFF) * DD + c2];
                #pragma unroll
                for (int i = 0; i < 8; ++i)
                    m[i] = *(const float2*)&emb12[(p[i] >> 17) & 15][c2];
                #pragma unroll
                for (int i = 0; i < 8; ++i) {
                    acc.x += bf2f_lo(hv[i]) + m[i].x;
                    acc.y += bf2f_hi(hv[i]) + m[i].y;
                }
            }
            for (; e < end; ++e) {
                int p = packed[e];
                unsigned int hv = *(const unsigned int*)&h[(size_t)(p & 0x1FFFF) * DD + c2];
                float2 m = *(const float2*)&emb12[(p >> 17) & 15][c2];
                acc.x += bf2f_lo(hv) + m.x;
                acc.y += bf2f_hi(hv) + m.y;
            }
        }
        *(unsigned int*)&aggl[r][c2] = ((unsigned int)f2bf(acc.y) << 16) | f2bf(acc.x);
    }
    __syncthreads();   // aggl complete

    // ---- MLP phase 1: hid = relu(aggl @ W1^T + b1) ----
    // wave w: row-frag rf = w&7 (16 rows), col-half ch = w>>3 (128 cols)
    const int rf = wid & 7, ch = wid >> 3;
    bf16x8 af[4];
    #pragma unroll
    for (int kf = 0; kf < 4; ++kf)
        af[kf] = *(const bf16x8*)&aggl[rf * 16 + rl][kf * 32 + kb];
    __syncthreads();   // all af loaded; U region free for hidl

    f32x4 acc1[8];
    const f32x4 zz = {0.f, 0.f, 0.f, 0.f};
    #pragma unroll
    for (int j = 0; j < 8; ++j) acc1[j] = zz;
    #pragma unroll
    for (int j = 0; j < 8; ++j) {
        int nt = ch * 8 + j;
        bf16x8 bf[4];
        #pragma unroll
        for (int kf = 0; kf < 4; ++kf)
            bf[kf] = *(const bf16x8*)&W1l[nt * 16 + rl][kf * 32 + kb];
        #pragma unroll
        for (int kf = 0; kf < 4; ++kf)
            acc1[j] = __builtin_amdgcn_mfma_f32_16x16x32_bf16(af[kf], bf[kf], acc1[j], 0, 0, 0);
    }
    #pragma unroll
    for (int j = 0; j < 8; ++j) {
        int c = (ch * 8 + j) * 16 + rl;
        float bi = b1[c];
        #pragma unroll
        for (int tt = 0; tt < 4; ++tt)
            hidl[rf * 16 + rq + tt][c] = f2bf(fmaxf(acc1[j][tt] + bi, 0.f));
    }
    __syncthreads();   // hidl complete; W1l reads done

    // stage W2 over W1l region
    for (int idx = t; idx < 128 * 32; idx += 1024) {
        int n = idx >> 5, kq = idx & 31;
        *(ushort4*)&W2l[n][kq * 8] = *(const ushort4*)&w2b[(size_t)n * 256 + kq * 8];
        *(ushort4*)&W2l[n][kq * 8 + 4] = *(const ushort4*)&w2b[(size_t)n * 256 + kq * 8 + 4];
    }
    // af2 from hidl (complete since last barrier)
    bf16x8 af2[8];
    #pragma unroll
    for (int kf = 0; kf < 8; ++kf)
        af2[kf] = *(const bf16x8*)&hidl[rf * 16 + rl][kf * 32 + kb];
    __syncthreads();   // W2l staged

    // ---- MLP phase 2: out = hidl @ W2^T + b2 ----
    // wave w: rows rf*16..+16, out-cols [ch*64, +64) -> 4 nt
    f32x4 acc2[4];
    #pragma unroll
    for (int j = 0; j < 4; ++j) acc2[j] = zz;
    #pragma unroll
    for (int j = 0; j < 4; ++j) {
        int nt = ch * 4 + j;
        bf16x8 bf[8];
        #pragma unroll
        for (int kf = 0; kf < 8; ++kf)
            bf[kf] = *(const bf16x8*)&W2l[nt * 16 + rl][kf * 32 + kb];
        #pragma unroll
        for (int kf = 0; kf < 8; ++kf)
            acc2[j] = __builtin_amdgcn_mfma_f32_16x16x32_bf16(af2[kf], bf[kf], acc2[j], 0, 0, 0);
    }
    #pragma unroll
    for (int j = 0; j < 4; ++j) {
        int c = (ch * 4 + j) * 16 + rl;
        float bi = b2[c];
        #pragma unroll
        for (int tt = 0; tt < 4; ++tt) {
            int r = n0 + rf * 16 + rq + tt;
            if (r < M) out[(size_t)r * 128 + c] = acc2[j][tt] + bi;
        }
    }
}

extern "C" void kernel_launch(void* const* d_in, const int* in_sizes, int n_in,
                              void* d_out, int out_size, void* d_ws, size_t ws_size,
                              hipStream_t stream) {
    const float* x     = (const float*)d_in[0];
    const int*   ei    = (const int*)d_in[1];
    const int*   ea    = (const int*)d_in[2];
    const float* pa    = (const float*)d_in[3];
    const float* Wenc  = (const float*)d_in[4];
    const float* emb1  = (const float*)d_in[5];
    const float* emb2  = (const float*)d_in[6];
    const float* W1    = (const float*)d_in[7];
    const float* b1    = (const float*)d_in[8];
    const float* W2    = (const float*)d_in[9];
    const float* b2    = (const float*)d_in[10];
    float* out = (float*)d_out;

    const int M = in_sizes[0] / DD;
    const int E = in_sizes[1] / 2;
    const int nsb = (M + SBN - 1) >> SBSH;          // 782
    const int chunk = (E + NBP - 1) / NBP;
    const int ntot = nsb * NBP;                     // ~200K
    const int nscb = (ntot + 2047) / 2048;          // 98 (<= 256)

    char* ws = (char*)d_ws;
    size_t o = 0;
    unsigned short* h_bf  = (unsigned short*)(ws + o); o += (size_t)M * DD * 2;
    int* rec    = (int*)(ws + o); o += (size_t)E * 4;
    int* packed = (int*)(ws + o); o += (size_t)E * 4;
    int* bh     = (int*)(ws + o); o += (size_t)ntot * 4;
    int* bho    = (int*)(ws + o); o += (size_t)ntot * 4;
    int* bsum   = (int*)(ws + o); o += (size_t)nscb * 4;
    unsigned short* wb = (unsigned short*)(ws + o); o += 81920 * 2;
    unsigned short* wenc_b = wb;
    unsigned short* w1_b   = wb + 16384;
    unsigned short* w2_b   = wb + 49152;

    const int gm = (M + 127) / 128;
    dim3 blk(256);

    // sbhist || wcvt
    sbwc_k<<<dim3(NBP + 80), blk, 0, stream>>>(ei, bh, Wenc, W1, W2, wb, E, chunk, nsb);

    pscan1_k<<<dim3(nscb), blk, 0, stream>>>(bh, bsum, ntot);
    pscan3_k<<<dim3(nscb), blk, 0, stream>>>(bh, bsum, bho, ntot);

    // part || gemm1
    pg_k<<<dim3(NBP + gm), blk, 0, stream>>>(
        ei, ea, bho, rec, x, wenc_b, h_bf, pa, E, chunk, nsb, M);

    // per-bucket sort + aggregate + MLP (fused)
    cam_k<<<dim3(nsb), dim3(1024), 0, stream>>>(
        h_bf, rec, bho, emb1, emb2, packed,
        w1_b, b1, w2_b, b2, out, nsb, M, E);
}

// Round 18
// 182.829 us; speedup vs baseline: 1.1190x; 1.1190x over previous
//
#include <hip/hip_runtime.h>
#include <hip/hip_bf16.h>

#define DD 128

typedef short bf16x8 __attribute__((ext_vector_type(8)));
typedef float f32x4 __attribute__((ext_vector_type(4)));

__device__ __forceinline__ float bf2f_lo(unsigned int u) {
    union { unsigned int v; float f; } x; x.v = u << 16; return x.f;
}
__device__ __forceinline__ float bf2f_hi(unsigned int u) {
    union { unsigned int v; float f; } x; x.v = u & 0xFFFF0000u; return x.f;
}
__device__ __forceinline__ unsigned short f2bf(float f) {
    union { float f; unsigned int u; } x; x.f = f;
    unsigned int u = x.u;
    unsigned int r = (u + 0x7FFFu + ((u >> 16) & 1u)) >> 16;  // RNE
    return (unsigned short)r;
}

// bucket geometry: 128 dsts per bucket, 256 partition blocks (all CUs)
#define SBSH 7
#define SBN  128
#define NBP  256
#define NSBMAX 800
#define PKCAP 4096

// ---- merged: [0,NBP) sbhist | [NBP,NBP+80) weight convert ----
__global__ __launch_bounds__(256) void sbwc_k(
    const int* __restrict__ ei, int* __restrict__ bh,
    const float* __restrict__ Wenc, const float* __restrict__ W1,
    const float* __restrict__ W2, unsigned short* __restrict__ wb,
    int E, int chunk, int nsb)
{
    __shared__ int h4[4][NSBMAX];
    const int b = blockIdx.x;
    if (b < NBP) {                               // ---- sbhist ----
        int wid = threadIdx.x >> 6;
        for (int i = threadIdx.x; i < 4 * NSBMAX; i += 256) ((int*)h4)[i] = 0;
        __syncthreads();
        int beg = b * chunk, end = min(E, beg + chunk);
        for (int e = beg + threadIdx.x; e < end; e += 256)
            atomicAdd(&h4[wid][ei[E + e] >> SBSH], 1);
        __syncthreads();
        for (int i = threadIdx.x; i < nsb; i += 256)
            bh[i * NBP + b] = h4[0][i] + h4[1][i] + h4[2][i] + h4[3][i];
        return;
    }
    // ---- wcvt: Wenc(16384) | W1(32768) | W2(32768) -> bf16 ----
    int i = ((b - NBP) * 256 + threadIdx.x) * 4;
    if (i >= 81920) return;
    const float* src;
    int off;
    if (i < 16384)      { src = Wenc; off = 0; }
    else if (i < 49152) { src = W1;   off = 16384; }
    else                { src = W2;   off = 49152; }
    float4 v = *(const float4*)&src[i - off];
    ushort4 w;
    w.x = f2bf(v.x); w.y = f2bf(v.y); w.z = f2bf(v.z); w.w = f2bf(v.w);
    *(ushort4*)&wb[i] = w;
}

// ---- parallel scan stage 1: per-block (2048 elems) totals ----
__global__ __launch_bounds__(256) void pscan1_k(const int* __restrict__ bh,
                                                int* __restrict__ bsum, int ntot) {
    __shared__ int ws[4];
    int base = blockIdx.x * 2048 + threadIdx.x * 8;
    int s = 0;
    #pragma unroll
    for (int i = 0; i < 8; ++i) { int idx = base + i; if (idx < ntot) s += bh[idx]; }
    int lane = threadIdx.x & 63, wid = threadIdx.x >> 6;
    int ss = s;
    #pragma unroll
    for (int o = 1; o < 64; o <<= 1) { int t = __shfl_up(ss, o, 64); if (lane >= o) ss += t; }
    if (lane == 63) ws[wid] = ss;
    __syncthreads();
    if (threadIdx.x == 0) bsum[blockIdx.x] = ws[0] + ws[1] + ws[2] + ws[3];
}

// ---- scan stage 2 (fused): each block derives its own bsum prefix ----
__global__ __launch_bounds__(256) void pscan3_k(const int* __restrict__ bh,
                                                const int* __restrict__ bsum,
                                                int* __restrict__ bho, int ntot) {
    __shared__ int ws[4];
    __shared__ int boff;
    const int b = blockIdx.x;
    const int t = threadIdx.x;
    const int lane = t & 63, wid = t >> 6;

    int pv = (t < b) ? bsum[t] : 0;
    #pragma unroll
    for (int o = 32; o; o >>= 1) pv += __shfl_xor(pv, o, 64);
    if (lane == 0) ws[wid] = pv;
    __syncthreads();
    if (t == 0) boff = ws[0] + ws[1] + ws[2] + ws[3];
    __syncthreads();

    int base = b * 2048 + t * 8;
    int v[8]; int s = 0;
    #pragma unroll
    for (int i = 0; i < 8; ++i) { int idx = base + i; v[i] = (idx < ntot) ? bh[idx] : 0; s += v[i]; }
    int ss = s;
    #pragma unroll
    for (int o = 1; o < 64; o <<= 1) { int u = __shfl_up(ss, o, 64); if (lane >= o) ss += u; }
    if (lane == 63) ws[wid] = ss;
    __syncthreads();
    if (t == 0) { int c = 0; for (int w = 0; w < 4; ++w) { int u = ws[w]; ws[w] = c; c += u; } }
    __syncthreads();
    int excl = ss - s + ws[wid] + boff;
    #pragma unroll
    for (int i = 0; i < 8; ++i) {
        int idx = base + i;
        if (idx < ntot) bho[idx] = excl;
        excl += v[i];
    }
}

// ---- merged: [0,NBP) partition | [NBP,NBP+gm) gemm1 ----
__global__ __launch_bounds__(256) void pg_k(
    const int* __restrict__ ei, const int* __restrict__ ea,
    const int* __restrict__ bho, int* __restrict__ rec,
    const float* __restrict__ x, const unsigned short* __restrict__ Wb,
    unsigned short* __restrict__ Hb, const float* __restrict__ prelu_a,
    int E, int chunk, int nsb, int M)
{
    __shared__ int cur[NSBMAX];
    const int tid = threadIdx.x;

    if (blockIdx.x < NBP) {                      // ---- part ----
        int b = blockIdx.x;
        for (int i = tid; i < nsb; i += 256) cur[i] = bho[i * NBP + b];
        __syncthreads();
        int beg = b * chunk, end = min(E, beg + chunk);
        for (int e = beg + tid; e < end; e += 256) {
            int src = ei[e];
            int dst = ei[E + e];
            int2 aa = *(const int2*)&ea[2 * e];
            int pos = atomicAdd(&cur[dst >> SBSH], 1);
            rec[pos] = src | ((aa.x * 3 + aa.y) << 17) | ((dst & (SBN - 1)) << 21);
        }
        return;
    }

    // ---- gemm1 ----
    const int K = 128;
    const int wid = tid >> 6, lane = tid & 63;
    const float pa = prelu_a[0];
    const int r0 = (blockIdx.x - NBP) * 128 + wid * 32;
    const int rl = lane & 15, kb = (lane >> 4) * 8;

    bf16x8 af[2][4];
    #pragma unroll
    for (int rf = 0; rf < 2; ++rf) {
        int row = r0 + rf * 16 + rl; if (row > M - 1) row = M - 1;
        #pragma unroll
        for (int kf = 0; kf < 4; ++kf) {
            float4 v0 = *(const float4*)&x[(size_t)row * K + kf * 32 + kb];
            float4 v1 = *(const float4*)&x[(size_t)row * K + kf * 32 + kb + 4];
            v0.x = v0.x >= 0.f ? v0.x : pa * v0.x;
            v0.y = v0.y >= 0.f ? v0.y : pa * v0.y;
            v0.z = v0.z >= 0.f ? v0.z : pa * v0.z;
            v0.w = v0.w >= 0.f ? v0.w : pa * v0.w;
            v1.x = v1.x >= 0.f ? v1.x : pa * v1.x;
            v1.y = v1.y >= 0.f ? v1.y : pa * v1.y;
            v1.z = v1.z >= 0.f ? v1.z : pa * v1.z;
            v1.w = v1.w >= 0.f ? v1.w : pa * v1.w;
            bf16x8 t;
            t[0] = (short)f2bf(v0.x); t[1] = (short)f2bf(v0.y);
            t[2] = (short)f2bf(v0.z); t[3] = (short)f2bf(v0.w);
            t[4] = (short)f2bf(v1.x); t[5] = (short)f2bf(v1.y);
            t[6] = (short)f2bf(v1.z); t[7] = (short)f2bf(v1.w);
            af[rf][kf] = t;
        }
    }

    f32x4 acc[8][2];
    const f32x4 zz = {0.f, 0.f, 0.f, 0.f};
    #pragma unroll
    for (int nt = 0; nt < 8; ++nt) { acc[nt][0] = zz; acc[nt][1] = zz; }

    #pragma unroll
    for (int nt = 0; nt < 8; ++nt) {
        bf16x8 bf[4];
        #pragma unroll
        for (int kf = 0; kf < 4; ++kf)
            bf[kf] = *(const bf16x8*)&Wb[(size_t)(nt * 16 + rl) * K + kf * 32 + kb];
        #pragma unroll
        for (int rf = 0; rf < 2; ++rf)
            #pragma unroll
            for (int kf = 0; kf < 4; ++kf)
                acc[nt][rf] = __builtin_amdgcn_mfma_f32_16x16x32_bf16(af[rf][kf], bf[kf], acc[nt][rf], 0, 0, 0);
    }

    const int rq = (lane >> 4) * 4;
    #pragma unroll
    for (int nt = 0; nt < 8; ++nt) {
        int c = nt * 16 + rl;
        #pragma unroll
        for (int rf = 0; rf < 2; ++rf) {
            int rb = r0 + rf * 16 + rq;
            #pragma unroll
            for (int t = 0; t < 4; ++t) {
                int r = rb + t;
                if (r < M) Hb[(size_t)r * 128 + c] = f2bf(acc[nt][rf][t]);
            }
        }
    }
}

// ---- fused per-bucket sort (into LDS) + gather-reduce ----
__global__ __launch_bounds__(1024) void csragg_k(
    const unsigned short* __restrict__ h,
    const int* __restrict__ rec,
    const int* __restrict__ bho,
    const float* __restrict__ emb1, const float* __restrict__ emb2,
    int* __restrict__ packed, unsigned int* __restrict__ aggb,
    int nsb, int M, int E)
{
    __shared__ float emb12[10][DD];
    __shared__ int hist[SBN];
    __shared__ int lstart[SBN];
    __shared__ int wsum[2];
    __shared__ int pkl[PKCAP];
    const int s = blockIdx.x;
    const int t = threadIdx.x;
    const int lane = t & 63, wid = t >> 6;

    for (int i = t; i < 10 * DD; i += 1024) {
        int c = i >> 7, col = i & 127;
        float v;
        if (c == 9) v = emb1[4 * DD + col] + emb2[col];          // self-loop emb
        else        v = emb1[(c / 3) * DD + col] + emb2[(c % 3) * DD + col];
        emb12[c][col] = v;
    }
    int sb0 = bho[s * NBP];
    int sb1 = (s == nsb - 1) ? E : bho[(s + 1) * NBP];
    if (t < SBN) hist[t] = 0;
    __syncthreads();

    const bool inlds = (sb1 - sb0) <= PKCAP;

    // bucket histogram
    for (int i = sb0 + t; i < sb1; i += 1024)
        atomicAdd(&hist[(rec[i] >> 21) & (SBN - 1)], 1);
    __syncthreads();

    // scan 128 bins (waves 0-1)
    int v = (t < SBN) ? hist[t] : 0;
    int ss = v;
    #pragma unroll
    for (int o = 1; o < 64; o <<= 1) { int u = __shfl_up(ss, o, 64); if (lane >= o) ss += u; }
    if (t < SBN && lane == 63) wsum[wid] = ss;
    __syncthreads();
    if (t == 0) { int c = 0; for (int w = 0; w < 2; ++w) { int x2 = wsum[w]; wsum[w] = c; c += x2; } }
    __syncthreads();
    if (t < SBN) {
        lstart[t] = ss - v + wsum[wid];
        hist[t] = 0;   // reuse as cursor; ends as per-dst count
    }
    __syncthreads();

    // scatter into dst-sorted order (LDS if it fits, else global window)
    if (inlds) {
        for (int i = sb0 + t; i < sb1; i += 1024) {
            int r = rec[i];
            int dl = (r >> 21) & (SBN - 1);
            int pos = lstart[dl] + atomicAdd(&hist[dl], 1);
            pkl[pos] = r & 0x1FFFFF;
        }
    } else {
        for (int i = sb0 + t; i < sb1; i += 1024) {
            int r = rec[i];
            int dl = (r >> 21) & (SBN - 1);
            int pos = sb0 + lstart[dl] + atomicAdd(&hist[dl], 1);
            packed[pos] = r & 0x1FFFFF;
        }
    }
    __syncthreads();

    // aggregate: 16 waves x 8 rows each
    const int n0 = s << SBSH;
    const int c2 = lane * 2;
    #pragma unroll
    for (int k = 0; k < SBN / 16; ++k) {
        int r = wid + k * 16;
        int n = n0 + r;
        if (n >= M) continue;
        int lbeg = lstart[r];
        int lend = lbeg + hist[r];
        unsigned int hn = *(const unsigned int*)&h[(size_t)n * DD + c2];
        float2 acc = {bf2f_lo(hn) + emb12[9][c2], bf2f_hi(hn) + emb12[9][c2 + 1]};
        if (inlds) {
            int e = lbeg;
            for (; e + 8 <= lend; e += 8) {
                int p[8]; unsigned int hv[8]; float2 m[8];
                #pragma unroll
                for (int i = 0; i < 8; ++i) p[i] = pkl[e + i];
                #pragma unroll
                for (int i = 0; i < 8; ++i)
                    hv[i] = *(const unsigned int*)&h[(size_t)(p[i] & 0x1FFFF) * DD + c2];
                #pragma unroll
                for (int i = 0; i < 8; ++i)
                    m[i] = *(const float2*)&emb12[(p[i] >> 17) & 15][c2];
                #pragma unroll
                for (int i = 0; i < 8; ++i) {
                    acc.x += bf2f_lo(hv[i]) + m[i].x;
                    acc.y += bf2f_hi(hv[i]) + m[i].y;
                }
            }
            for (; e < lend; ++e) {
                int p = pkl[e];
                unsigned int hv = *(const unsigned int*)&h[(size_t)(p & 0x1FFFF) * DD + c2];
                float2 m = *(const float2*)&emb12[(p >> 17) & 15][c2];
                acc.x += bf2f_lo(hv) + m.x;
                acc.y += bf2f_hi(hv) + m.y;
            }
        } else {
            int e = sb0 + lbeg, end = sb0 + lend;
            for (; e + 8 <= end; e += 8) {
                int p[8]; unsigned int hv[8]; float2 m[8];
                #pragma unroll
                for (int i = 0; i < 8; ++i) p[i] = packed[e + i];
                #pragma unroll
                for (int i = 0; i < 8; ++i)
                    hv[i] = *(const unsigned int*)&h[(size_t)(p[i] & 0x1FFFF) * DD + c2];
                #pragma unroll
                for (int i = 0; i < 8; ++i)
                    m[i] = *(const float2*)&emb12[(p[i] >> 17) & 15][c2];
                #pragma unroll
                for (int i = 0; i < 8; ++i) {
                    acc.x += bf2f_lo(hv[i]) + m[i].x;
                    acc.y += bf2f_hi(hv[i]) + m[i].y;
                }
            }
            for (; e < end; ++e) {
                int p = packed[e];
                unsigned int hv = *(const unsigned int*)&h[(size_t)(p & 0x1FFFF) * DD + c2];
                float2 m = *(const float2*)&emb12[(p >> 17) & 15][c2];
                acc.x += bf2f_lo(hv) + m.x;
                acc.y += bf2f_hi(hv) + m.y;
            }
        }
        aggb[((size_t)n * DD + c2) >> 1] = ((unsigned int)f2bf(acc.y) << 16) | f2bf(acc.x);
    }
}

// ---- fused MLP (16-wave variant, decomposition validated in r17's cam_k) ----
__global__ __launch_bounds__(1024) void mlp_k(
    const unsigned short* __restrict__ A,    // aggb [M][128] bf16
    const unsigned short* __restrict__ w1b,
    const float* __restrict__ b1,
    const unsigned short* __restrict__ w2b,
    const float* __restrict__ b2,
    float* __restrict__ out, int M)
{
    __shared__ unsigned short W1l[256][136];     // 69632 B; W2l aliases
    __shared__ unsigned short hidl[128][264];    // 67584 B
    unsigned short (*W2l)[264] = (unsigned short (*)[264])&W1l[0][0];

    const int tid = threadIdx.x;
    const int wid = tid >> 6, lane = tid & 63;   // 16 waves
    const int rl = lane & 15, kb = (lane >> 4) * 8;
    const int rq = (lane >> 4) * 4;
    const int rf = wid & 7, ch = wid >> 3;       // 8 row-frags x 2 col-halves
    const int r0 = blockIdx.x * 128;

    // stage W1 (bf16 copy)
    for (int idx = tid; idx < 256 * 16; idx += 1024) {
        int n = idx >> 4, kq = idx & 15;
        *(ushort4*)&W1l[n][kq * 8] = *(const ushort4*)&w1b[(size_t)n * 128 + kq * 8];
        *(ushort4*)&W1l[n][kq * 8 + 4] = *(const ushort4*)&w1b[(size_t)n * 128 + kq * 8 + 4];
    }
    bf16x8 af[4];
    {
        int row = r0 + rf * 16 + rl; if (row > M - 1) row = M - 1;
        #pragma unroll
        for (int kf = 0; kf < 4; ++kf)
            af[kf] = *(const bf16x8*)&A[(size_t)row * 128 + kf * 32 + kb];
    }
    __syncthreads();

    // phase 1: hid rows [rf*16,+16) x cols [ch*128,+128)
    f32x4 acc1[8];
    const f32x4 zz = {0.f, 0.f, 0.f, 0.f};
    #pragma unroll
    for (int j = 0; j < 8; ++j) acc1[j] = zz;
    #pragma unroll
    for (int j = 0; j < 8; ++j) {
        int nt = ch * 8 + j;
        bf16x8 bf[4];
        #pragma unroll
        for (int kf = 0; kf < 4; ++kf)
            bf[kf] = *(const bf16x8*)&W1l[nt * 16 + rl][kf * 32 + kb];
        #pragma unroll
        for (int kf = 0; kf < 4; ++kf)
            acc1[j] = __builtin_amdgcn_mfma_f32_16x16x32_bf16(af[kf], bf[kf], acc1[j], 0, 0, 0);
    }
    #pragma unroll
    for (int j = 0; j < 8; ++j) {
        int c = (ch * 8 + j) * 16 + rl;
        float bi = b1[c];
        #pragma unroll
        for (int tt = 0; tt < 4; ++tt)
            hidl[rf * 16 + rq + tt][c] = f2bf(fmaxf(acc1[j][tt] + bi, 0.f));
    }
    __syncthreads();   // hidl complete; W1l reads done

    // stage W2 over W1l region; af2 from hidl
    for (int idx = tid; idx < 128 * 32; idx += 1024) {
        int n = idx >> 5, kq = idx & 31;
        *(ushort4*)&W2l[n][kq * 8] = *(const ushort4*)&w2b[(size_t)n * 256 + kq * 8];
        *(ushort4*)&W2l[n][kq * 8 + 4] = *(const ushort4*)&w2b[(size_t)n * 256 + kq * 8 + 4];
    }
    bf16x8 af2[8];
    #pragma unroll
    for (int kf = 0; kf < 8; ++kf)
        af2[kf] = *(const bf16x8*)&hidl[rf * 16 + rl][kf * 32 + kb];
    __syncthreads();   // W2l staged

    // phase 2: out rows [rf*16,+16) x cols [ch*64,+64)
    f32x4 acc2[4];
    #pragma unroll
    for (int j = 0; j < 4; ++j) acc2[j] = zz;
    #pragma unroll
    for (int j = 0; j < 4; ++j) {
        int nt = ch * 4 + j;
        bf16x8 bf[8];
        #pragma unroll
        for (int kf = 0; kf < 8; ++kf)
            bf[kf] = *(const bf16x8*)&W2l[nt * 16 + rl][kf * 32 + kb];
        #pragma unroll
        for (int kf = 0; kf < 8; ++kf)
            acc2[j] = __builtin_amdgcn_mfma_f32_16x16x32_bf16(af2[kf], bf[kf], acc2[j], 0, 0, 0);
    }
    #pragma unroll
    for (int j = 0; j < 4; ++j) {
        int c = (ch * 4 + j) * 16 + rl;
        float bi = b2[c];
        #pragma unroll
        for (int tt = 0; tt < 4; ++tt) {
            int r = r0 + rf * 16 + rq + tt;
            if (r < M) out[(size_t)r * 128 + c] = acc2[j][tt] + bi;
        }
    }
}

extern "C" void kernel_launch(void* const* d_in, const int* in_sizes, int n_in,
                              void* d_out, int out_size, void* d_ws, size_t ws_size,
                              hipStream_t stream) {
    const float* x     = (const float*)d_in[0];
    const int*   ei    = (const int*)d_in[1];
    const int*   ea    = (const int*)d_in[2];
    const float* pa    = (const float*)d_in[3];
    const float* Wenc  = (const float*)d_in[4];
    const float* emb1  = (const float*)d_in[5];
    const float* emb2  = (const float*)d_in[6];
    const float* W1    = (const float*)d_in[7];
    const float* b1    = (const float*)d_in[8];
    const float* W2    = (const float*)d_in[9];
    const float* b2    = (const float*)d_in[10];
    float* out = (float*)d_out;

    const int M = in_sizes[0] / DD;
    const int E = in_sizes[1] / 2;
    const int nsb = (M + SBN - 1) >> SBSH;          // 782
    const int chunk = (E + NBP - 1) / NBP;
    const int ntot = nsb * NBP;                     // ~200K
    const int nscb = (ntot + 2047) / 2048;          // 98 (<= 256)

    char* ws = (char*)d_ws;
    size_t o = 0;
    unsigned short* h_bf  = (unsigned short*)(ws + o); o += (size_t)M * DD * 2;
    unsigned int*   aggb  = (unsigned int*)(ws + o);   o += (size_t)M * DD * 2;
    int* rec    = (int*)(ws + o); o += (size_t)E * 4;
    int* packed = (int*)(ws + o); o += (size_t)E * 4;
    int* bh     = (int*)(ws + o); o += (size_t)ntot * 4;
    int* bho    = (int*)(ws + o); o += (size_t)ntot * 4;
    int* bsum   = (int*)(ws + o); o += (size_t)nscb * 4;
    unsigned short* wb = (unsigned short*)(ws + o); o += 81920 * 2;
    unsigned short* wenc_b = wb;
    unsigned short* w1_b   = wb + 16384;
    unsigned short* w2_b   = wb + 49152;

    const int gm = (M + 127) / 128;
    dim3 blk(256);

    // sbhist || wcvt
    sbwc_k<<<dim3(NBP + 80), blk, 0, stream>>>(ei, bh, Wenc, W1, W2, wb, E, chunk, nsb);

    pscan1_k<<<dim3(nscb), blk, 0, stream>>>(bh, bsum, ntot);
    pscan3_k<<<dim3(nscb), blk, 0, stream>>>(bh, bsum, bho, ntot);

    // part || gemm1
    pg_k<<<dim3(NBP + gm), blk, 0, stream>>>(
        ei, ea, bho, rec, x, wenc_b, h_bf, pa, E, chunk, nsb, M);

    // per-bucket sort + aggregate
    csragg_k<<<dim3(nsb), dim3(1024), 0, stream>>>(
        h_bf, rec, bho, emb1, emb2, packed, aggb, nsb, M, E);

    // out = relu(aggb @ W1^T + b1) @ W2^T + b2
    mlp_k<<<dim3(gm), dim3(1024), 0, stream>>>(
        (const unsigned short*)aggb, w1_b, b1, w2_b, b2, out, M);
}